// Round 12
// baseline (321.671 us; speedup 1.0000x reference)
//
#include <hip/hip_runtime.h>
#include <hip/hip_bf16.h>

#define B_ 8
#define T_ 4096
#define D_ 1024
#define H_ 1024

typedef __attribute__((ext_vector_type(8))) short short8;
typedef __attribute__((ext_vector_type(4))) float floatx4;

#define GLOAD16(gptr, lptr) \
  __builtin_amdgcn_global_load_lds((const __attribute__((address_space(1))) void*)(gptr), \
                                   (__attribute__((address_space(3))) void*)(lptr), 16, 0, 0)

__device__ __forceinline__ ushort f2b(float f) {
  unsigned x = __builtin_bit_cast(unsigned, f);
  unsigned r = (x + 0x7fffu + ((x >> 16) & 1u)) >> 16;  // RNE, inputs finite
  return (ushort)r;
}

__global__ void cvt_kernel(const float* __restrict__ in, ushort* __restrict__ out, int n) {
  int idx = blockIdx.x * blockDim.x + threadIdx.x;
  int stride = gridDim.x * blockDim.x;
  for (long i = (long)idx * 8; i < n; i += (long)stride * 8) {
    const float4 f0 = *(const float4*)(in + i);
    const float4 f1 = *(const float4*)(in + i + 4);
    union { ushort u[8]; uint4 v; } r;
    r.u[0] = f2b(f0.x); r.u[1] = f2b(f0.y); r.u[2] = f2b(f0.z); r.u[3] = f2b(f0.w);
    r.u[4] = f2b(f1.x); r.u[5] = f2b(f1.y); r.u[6] = f2b(f1.z); r.u[7] = f2b(f1.w);
    *(uint4*)(out + i) = r.v;
  }
}

__global__ void cvt3_kernel(const float* __restrict__ w0, const float* __restrict__ w1,
                            const float* __restrict__ w2, ushort* __restrict__ out, int n) {
  const float* in = (blockIdx.y == 0) ? w0 : (blockIdx.y == 1) ? w1 : w2;
  ushort* o = out + (size_t)blockIdx.y * n;
  int idx = blockIdx.x * blockDim.x + threadIdx.x;
  int stride = gridDim.x * blockDim.x;
  for (long i = (long)idx * 8; i < n; i += (long)stride * 8) {
    const float4 f0 = *(const float4*)(in + i);
    const float4 f1 = *(const float4*)(in + i + 4);
    union { ushort u[8]; uint4 v; } r;
    r.u[0] = f2b(f0.x); r.u[1] = f2b(f0.y); r.u[2] = f2b(f0.z); r.u[3] = f2b(f0.w);
    r.u[4] = f2b(f1.x); r.u[5] = f2b(f1.y); r.u[6] = f2b(f1.z); r.u[7] = f2b(f1.w);
    *(uint4*)(o + i) = r.v;
  }
}

// K1: fused K/V GEMM + batch reduction — MULTI-BLOCK config (R12).
// Block 128t x 64h, 4 waves (2t x 2h), wave tile 64t x 32h (m4 n2).
// STATIC 48 KiB LDS (3 bufs x [A 8K | K 4K | V 4K]) -> 2-3 blocks/CU:
// inter-block wave mixing hides the post-barrier ds_read flood + vmcnt tail
// (the invariant across all prior ~145us kv variants was 1 block/CU).
// Counted vmcnt(4): stage(p+2) issued at p, wait leaves 4 in flight ->
// stage(p+1) landed; never drains to 0 in steady state. 1 barrier/phase.
// Swizzle both sides (4 chunks/row): chunk' = chunk ^ ((row>>1)&3).
// XCD swizzle: lid=(bid&7)*64+(bid>>3) -> XCD owns 4 t-panels x 16 h-panels.
__global__ __launch_bounds__(256, 2) void kv_kernel(
    const ushort* __restrict__ xb, const ushort* __restrict__ Wkb,
    const ushort* __restrict__ Wvb, const float* __restrict__ bk,
    const float* __restrict__ bv, const float* __restrict__ wbias,
    float* __restrict__ weighted) {
  __shared__ ushort As[3][128 * 32];  // 8 KiB / buf
  __shared__ ushort Ks[3][64 * 32];   // 4 KiB / buf
  __shared__ ushort Vs[3][64 * 32];   // 4 KiB / buf

  const int tid = threadIdx.x;
  const int lane = tid & 63;
  const int w = tid >> 6;       // 0..3
  const int wrow = w >> 1;      // 0..1  (64-row granule)
  const int wcol = w & 1;       // 0..1  (32-col granule)

  const int bid = blockIdx.x;               // 512 blocks
  const int lid = (bid & 7) * 64 + (bid >> 3);
  const int t0 = (lid >> 4) * 128;          // t-panel 0..31
  const int h0 = (lid & 15) * 64;           // h-panel 0..15

  // staging: A chunks ci = j*256+tid (j=0,1): row = ci>>2 = j*64 + (tid>>2),
  // phys = tid&3; source logical = phys ^ ((row>>1)&3) = (tid&3)^((tid>>3)&3)
  // (j*64>>1 = 32 ≡ 0 mod 4). K/V: ci = tid, row = tid>>2 (0..63), same.
  const int rA = tid >> 2;                       // 0..63
  const int lc = (tid & 3) ^ ((tid >> 3) & 3);

  const ushort* xsb = xb + (size_t)(t0 + rA) * D_ + lc * 8;
  const ushort* ksb = Wkb + (size_t)(h0 + rA) * D_ + lc * 8;
  const ushort* vsb = Wvb + (size_t)(h0 + rA) * D_ + lc * 8;

  auto stage = [&](int p, int buf) {  // 4 loads/thread
    const int b = p >> 5;
    const int kt = (p & 31) << 5;
    const ushort* xs = xsb + (size_t)b * (T_ * D_) + kt;
    GLOAD16(xs, &As[buf][tid * 8]);
    GLOAD16(xs + (size_t)64 * D_, &As[buf][(256 + tid) * 8]);
    GLOAD16(ksb + kt, &Ks[buf][tid * 8]);
    GLOAD16(vsb + kt, &Vs[buf][tid * 8]);
  };

  // fragment reads: row*32 + phys*8; phys = (lane>>4) ^ ((row>>1)&3);
  // (row>>1)&3 = ((lane&15)>>1)&3 (wrow*64, wcol*32, m/n*16 all ≡ 0 mod 8).
  const int sw = ((lane & 15) >> 1) & 3;
  const int aBase = (wrow * 64 + (lane & 15)) * 32 + ((lane >> 4) ^ sw) * 8;  // +m*512
  const int bBase = (wcol * 32 + (lane & 15)) * 32 + ((lane >> 4) ^ sw) * 8;  // +n*512

  float wbc[2], bkc[2], bvc[2];
#pragma unroll
  for (int n = 0; n < 2; ++n) {
    int h = h0 + wcol * 32 + n * 16 + (lane & 15);
    wbc[n] = wbias[h];
    bkc[n] = bk[h];
    bvc[n] = bv[h];
  }

  floatx4 accK[4][2] = {};
  floatx4 accV[4][2] = {};
  floatx4 sumN[4][2] = {};
  floatx4 sumWV[4][2] = {};

  stage(0, 0);
  stage(1, 1);
  asm volatile("s_waitcnt vmcnt(4)" ::: "memory");  // stage(0) landed
  __builtin_amdgcn_s_barrier();

  int cur = 0, stg = 2;
  for (int p = 0; p < 256; ++p) {  // 8 b x 32 K-steps
    if (p < 254) stage(p + 2, stg);

    const ushort* Ac = As[cur];
    const ushort* Kc = Ks[cur];
    const ushort* Vc = Vs[cur];
    short8 a[4], kf[2], vf[2];
#pragma unroll
    for (int m = 0; m < 4; ++m) a[m] = *(const short8*)(Ac + aBase + m * 512);
#pragma unroll
    for (int n = 0; n < 2; ++n) {
      kf[n] = *(const short8*)(Kc + bBase + n * 512);
      vf[n] = *(const short8*)(Vc + bBase + n * 512);
    }
#pragma unroll
    for (int m = 0; m < 4; ++m)
#pragma unroll
      for (int n = 0; n < 2; ++n) {
        accK[m][n] = __builtin_amdgcn_mfma_f32_16x16x32_bf16(a[m], kf[n], accK[m][n], 0, 0, 0);
        accV[m][n] = __builtin_amdgcn_mfma_f32_16x16x32_bf16(a[m], vf[n], accV[m][n], 0, 0, 0);
      }

    if ((p & 31) == 31) {  // end of batch: fold exp-weighted sums, reset acc
#pragma unroll
      for (int m = 0; m < 4; ++m)
#pragma unroll
        for (int n = 0; n < 2; ++n) {
#pragma unroll
          for (int r = 0; r < 4; ++r) {
            float nmr = __expf(accK[m][n][r] + bkc[n] + wbc[n]);
            sumN[m][n][r] += nmr;
            sumWV[m][n][r] += nmr * (accV[m][n][r] + bvc[n]);
          }
          accK[m][n] = floatx4{0.f, 0.f, 0.f, 0.f};
          accV[m][n] = floatx4{0.f, 0.f, 0.f, 0.f};
        }
    }

    if (p < 254) { asm volatile("s_waitcnt vmcnt(4)" ::: "memory"); }
    else         { asm volatile("s_waitcnt vmcnt(0)" ::: "memory"); }
    __builtin_amdgcn_s_barrier();
    cur = (cur == 2) ? 0 : cur + 1;
    stg = (stg == 2) ? 0 : stg + 1;
  }

  // C/D layout: col = lane&15, row = (lane>>4)*4 + r
#pragma unroll
  for (int m = 0; m < 4; ++m)
#pragma unroll
    for (int n = 0; n < 2; ++n)
#pragma unroll
      for (int r = 0; r < 4; ++r) {
        int t = t0 + wrow * 64 + m * 16 + (lane >> 4) * 4 + r;
        int h = h0 + wcol * 32 + n * 16 + (lane & 15);
        weighted[(size_t)t * H_ + h] = sumWV[m][n][r] / sumN[m][n][r];
      }
}

// K2: Q GEMM + sigmoid(Q)*weighted epilogue (R10, passed @~95us).
__global__ __launch_bounds__(512, 2) void q_kernel(
    const ushort* __restrict__ Am, const ushort* __restrict__ Bm,
    const float* __restrict__ bq, const float* __restrict__ weighted,
    float* __restrict__ out) {
  extern __shared__ ushort lds[];

  const int tid = threadIdx.x;
  const int lane = tid & 63;
  const int w = tid >> 6;     // 0..7
  const int wr = w >> 2;      // 0..1  (128-row granule)
  const int wc = w & 3;       // 0..3  (64-col granule)

  const int bid = blockIdx.x;               // 512 blocks
  const int lid = (bid & 7) * 64 + (bid >> 3);
  const int R0 = (lid >> 2) * 256;          // row-panel 0..127
  const int C0 = (lid & 3) * 256;           // col-panel 0..3

  const int r0 = tid >> 2;                       // 0..127
  const int lc = (tid & 3) ^ ((tid >> 3) & 3);
  const ushort* asrc = Am + (size_t)(R0 + r0) * D_ + lc * 8;
  const ushort* bsrc = Bm + (size_t)(C0 + r0) * D_ + lc * 8;

  auto stage = [&](int t) {  // 4 gloads/thread
    const int nb = t & 3;
    const int kt = t * 32;
    GLOAD16(asrc + kt, lds + nb * 8192 + tid * 8);
    GLOAD16(asrc + kt + (size_t)128 * D_, lds + nb * 8192 + (512 + tid) * 8);
    GLOAD16(bsrc + kt, lds + 32768 + nb * 8192 + tid * 8);
    GLOAD16(bsrc + kt + (size_t)128 * D_, lds + 32768 + nb * 8192 + (512 + tid) * 8);
  };

  const int baseA = wr * 128 + (lane & 15);
  const int baseB = wc * 64 + (lane & 15);
  const int aOff = baseA * 32 + ((lane >> 4) ^ ((baseA >> 1) & 3)) * 8;
  const int bOff = baseB * 32 + ((lane >> 4) ^ ((baseB >> 1) & 3)) * 8;

  floatx4 acc[8][4] = {};

  stage(0); stage(1);
  asm volatile("s_waitcnt vmcnt(4)" ::: "memory");  // tile 0 landed
  __builtin_amdgcn_s_barrier();

  const int NT = D_ / 32;  // 32
  for (int t = 0; t < NT; ++t) {
    if (t < NT - 2) stage(t + 2);
    const ushort* Ab = lds + (t & 3) * 8192;
    const ushort* Bb = lds + 32768 + (t & 3) * 8192;

    short8 b[4], a[8];
#pragma unroll
    for (int n = 0; n < 4; ++n) b[n] = *(const short8*)(Bb + bOff + n * 512);
#pragma unroll
    for (int m = 0; m < 8; ++m) a[m] = *(const short8*)(Ab + aOff + m * 512);
#pragma unroll
    for (int m = 0; m < 8; ++m)
#pragma unroll
      for (int n = 0; n < 4; ++n)
        acc[m][n] = __builtin_amdgcn_mfma_f32_16x16x32_bf16(a[m], b[n], acc[m][n], 0, 0, 0);

    if (t < NT - 2) { asm volatile("s_waitcnt vmcnt(4)" ::: "memory"); }
    else            { asm volatile("s_waitcnt vmcnt(0)" ::: "memory"); }
    __builtin_amdgcn_s_barrier();
  }

  // ---- epilogue: in-LDS transpose, 2 m-halves, coalesced stores ----
  const int lrb = wr * 64 + (lane >> 4) * 4;  // + mi*16 + r  (0..127)
  const int lcol = wc * 64 + (lane & 15);     // + n*16
#pragma unroll
  for (int mh = 0; mh < 2; ++mh) {
    if (mh) __builtin_amdgcn_s_barrier();
    float* lf = (float*)lds;  // 128 x 256 fp32 = 128 KiB
#pragma unroll
    for (int mi = 0; mi < 4; ++mi)
#pragma unroll
      for (int n = 0; n < 4; ++n)
#pragma unroll
        for (int r = 0; r < 4; ++r)
          lf[(lrb + mi * 16 + r) * 256 + lcol + n * 16] = acc[mh * 4 + mi][n][r];
    __builtin_amdgcn_s_barrier();
#pragma unroll
    for (int j = 0; j < 16; ++j) {
      int cidx = j * 512 + tid;    // 0..8191 float4 chunks
      int lr = cidx >> 6;
      int cc = cidx & 63;
      int grow = R0 + (lr >> 6) * 128 + mh * 64 + (lr & 63);
      float4 v = *(float4*)(lf + lr * 256 + cc * 4);
      float4 bq4 = *(const float4*)(bq + C0 + cc * 4);
      float4 wv = *(const float4*)(weighted + (size_t)(grow & (T_ - 1)) * H_ + C0 + cc * 4);
      float4 o;
      o.x = wv.x / (1.f + __expf(-(v.x + bq4.x)));
      o.y = wv.y / (1.f + __expf(-(v.y + bq4.y)));
      o.z = wv.z / (1.f + __expf(-(v.z + bq4.z)));
      o.w = wv.w / (1.f + __expf(-(v.w + bq4.w)));
      *(float4*)(out + (size_t)grow * H_ + C0 + cc * 4) = o;
    }
  }
}

extern "C" void kernel_launch(void* const* d_in, const int* in_sizes, int n_in,
                              void* d_out, int out_size, void* d_ws, size_t ws_size,
                              hipStream_t stream) {
  (void)in_sizes; (void)n_in; (void)out_size; (void)ws_size;
  const float* x = (const float*)d_in[0];
  const float* Wq = (const float*)d_in[1];
  const float* bq = (const float*)d_in[2];
  const float* Wk = (const float*)d_in[3];
  const float* bk = (const float*)d_in[4];
  const float* Wv = (const float*)d_in[5];
  const float* bv = (const float*)d_in[6];
  const float* wbias = (const float*)d_in[7];
  float* out = (float*)d_out;

  char* ws = (char*)d_ws;
  const size_t XN = (size_t)B_ * T_ * D_;   // 33,554,432
  const size_t WN = (size_t)H_ * D_;        // 1,048,576
  ushort* xb  = (ushort*)ws;                             // 64 MiB
  ushort* Wqb = (ushort*)(ws + XN * 2);                  // 2 MiB
  ushort* Wkb = Wqb + WN;                                // 2 MiB
  ushort* Wvb = Wkb + WN;                                // 2 MiB
  float* weighted = (float*)(ws + XN * 2 + 3 * WN * 2);  // 16 MiB

  (void)hipFuncSetAttribute((const void*)q_kernel,
                            hipFuncAttributeMaxDynamicSharedMemorySize, 131072);

  cvt_kernel<<<2048, 256, 0, stream>>>(x, xb, (int)XN);
  cvt3_kernel<<<dim3(512, 3), 256, 0, stream>>>(Wq, Wk, Wv, Wqb, (int)WN);

  kv_kernel<<<512, 256, 0, stream>>>(xb, Wkb, Wvb, bk, bv, wbias, weighted);
  q_kernel<<<512, 512, 131072, stream>>>(xb, Wqb, bq, weighted, out);
}

// Round 13
// 275.454 us; speedup vs baseline: 1.1678x; 1.1678x over previous
//
#include <hip/hip_runtime.h>
#include <hip/hip_bf16.h>

#define B_ 8
#define T_ 4096
#define D_ 1024
#define H_ 1024

typedef __attribute__((ext_vector_type(8))) short short8;
typedef __attribute__((ext_vector_type(4))) float floatx4;

#define GLOAD16(gptr, lptr) \
  __builtin_amdgcn_global_load_lds((const __attribute__((address_space(1))) void*)(gptr), \
                                   (__attribute__((address_space(3))) void*)(lptr), 16, 0, 0)

__device__ __forceinline__ ushort f2b(float f) {
  unsigned x = __builtin_bit_cast(unsigned, f);
  unsigned r = (x + 0x7fffu + ((x >> 16) & 1u)) >> 16;  // RNE, inputs finite
  return (ushort)r;
}

__global__ void cvt_kernel(const float* __restrict__ in, ushort* __restrict__ out, int n) {
  int idx = blockIdx.x * blockDim.x + threadIdx.x;
  int stride = gridDim.x * blockDim.x;
  for (long i = (long)idx * 8; i < n; i += (long)stride * 8) {
    const float4 f0 = *(const float4*)(in + i);
    const float4 f1 = *(const float4*)(in + i + 4);
    union { ushort u[8]; uint4 v; } r;
    r.u[0] = f2b(f0.x); r.u[1] = f2b(f0.y); r.u[2] = f2b(f0.z); r.u[3] = f2b(f0.w);
    r.u[4] = f2b(f1.x); r.u[5] = f2b(f1.y); r.u[6] = f2b(f1.z); r.u[7] = f2b(f1.w);
    *(uint4*)(out + i) = r.v;
  }
}

__global__ void cvt3_kernel(const float* __restrict__ w0, const float* __restrict__ w1,
                            const float* __restrict__ w2, ushort* __restrict__ out, int n) {
  const float* in = (blockIdx.y == 0) ? w0 : (blockIdx.y == 1) ? w1 : w2;
  ushort* o = out + (size_t)blockIdx.y * n;
  int idx = blockIdx.x * blockDim.x + threadIdx.x;
  int stride = gridDim.x * blockDim.x;
  for (long i = (long)idx * 8; i < n; i += (long)stride * 8) {
    const float4 f0 = *(const float4*)(in + i);
    const float4 f1 = *(const float4*)(in + i + 4);
    union { ushort u[8]; uint4 v; } r;
    r.u[0] = f2b(f0.x); r.u[1] = f2b(f0.y); r.u[2] = f2b(f0.z); r.u[3] = f2b(f0.w);
    r.u[4] = f2b(f1.x); r.u[5] = f2b(f1.y); r.u[6] = f2b(f1.z); r.u[7] = f2b(f1.w);
    *(uint4*)(o + i) = r.v;
  }
}

// K1: fused K/V GEMM + batch reduction, BATCH-PAIRED (R11 best: kv ~144.5us).
// Block 256t x 64h, 8 waves (4t x 2h), wave tile 64t x 32h (m4 n2).
// Each phase = one BK=32 K-step for TWO batches: Wk/Wv fragments are
// b-invariant, read once (4 ds_read) and feed both batches' MFMAs (64 total);
// A-frags 8 reads (4 per batch). acc doubles (accK/accV x2b = 128 VGPR).
// Triple-buffered LDS (120 KiB), counted vmcnt(5), 1 barrier/phase.
// Swizzle both sides (4 chunks/row): chunk' = chunk ^ ((row>>1)&3).
// XCD swizzle: lid=(bid&7)*32+(bid>>3) -> each XCD = 2 t-panels x 16 h-panels.
__global__ __launch_bounds__(512, 2) void kv_kernel(
    const ushort* __restrict__ xb, const ushort* __restrict__ Wkb,
    const ushort* __restrict__ Wvb, const float* __restrict__ bk,
    const float* __restrict__ bv, const float* __restrict__ wbias,
    float* __restrict__ weighted) {
  extern __shared__ ushort lds[];
  ushort* const AsB = lds;           // 3 bufs x [2 b][256x32] = 3x16384 elems
  ushort* const BsB = lds + 49152;   // 3 bufs x [K|V][64x32]  = 3x4096 elems

  const int tid = threadIdx.x;
  const int lane = tid & 63;
  const int w = tid >> 6;       // 0..7
  const int wrow = w >> 1;      // 0..3  (64-row granule)
  const int wcol = w & 1;       // 0..1  (32-col granule)

  const int bid = blockIdx.x;               // 256 blocks
  const int lid = (bid & 7) * 32 + (bid >> 3);
  const int t0 = (lid >> 4) * 256;          // t-panel 0..15
  const int h0 = (lid & 15) * 64;           // h-panel 0..15

  const int rA = tid >> 2;                        // 0..127
  const int lcA = (tid & 3) ^ ((tid >> 3) & 3);
  const int ci = tid & 255;
  const int rB = ci >> 2;                         // 0..63
  const int lcB = (ci & 3) ^ ((ci >> 3) & 3);

  const ushort* xsb = xb + (size_t)(t0 + rA) * D_ + lcA * 8;
  const ushort* wsrc = ((tid < 256) ? Wkb : Wvb) + (size_t)(h0 + rB) * D_ + lcB * 8;

  auto stage = [&](int p, int buf) {  // 5 loads/thread
    const int b0 = (p >> 5) * 2;
    const int kt = (p & 31) << 5;
    const ushort* x0 = xsb + (size_t)b0 * (T_ * D_) + kt;
    ushort* Ab = AsB + buf * 16384;
    GLOAD16(x0, Ab + tid * 8);
    GLOAD16(x0 + (size_t)128 * D_, Ab + (512 + tid) * 8);
    GLOAD16(x0 + (size_t)(T_ * D_), Ab + (1024 + tid) * 8);
    GLOAD16(x0 + (size_t)(T_ * D_ + 128 * D_), Ab + (1536 + tid) * 8);
    GLOAD16(wsrc + kt, BsB + buf * 4096 + tid * 8);
  };

  const int sw = ((lane & 15) >> 1) & 3;
  const int aBase = (wrow * 64 + (lane & 15)) * 32 + ((lane >> 4) ^ sw) * 8;  // +m*512, +b*8192
  const int bBase = (wcol * 32 + (lane & 15)) * 32 + ((lane >> 4) ^ sw) * 8;  // +n*512 (+2048 for V)

  float wbc[2], bkc[2], bvc[2];
#pragma unroll
  for (int n = 0; n < 2; ++n) {
    int h = h0 + wcol * 32 + n * 16 + (lane & 15);
    wbc[n] = wbias[h];
    bkc[n] = bk[h];
    bvc[n] = bv[h];
  }

  floatx4 accK[2][4][2] = {};
  floatx4 accV[2][4][2] = {};
  floatx4 sumN[4][2] = {};
  floatx4 sumWV[4][2] = {};

  stage(0, 0);
  stage(1, 1);
  asm volatile("s_waitcnt vmcnt(5)" ::: "memory");  // stage(0) landed
  __builtin_amdgcn_s_barrier();

  int cur = 0, stg = 2;
  for (int p = 0; p < 128; ++p) {  // 4 b-pairs x 32 K-steps
    if (p < 126) stage(p + 2, stg);

    const ushort* Ab = AsB + cur * 16384;
    const ushort* Bb = BsB + cur * 4096;
    short8 kf[2], vf[2], af[4];
    kf[0] = *(const short8*)(Bb + bBase);
    kf[1] = *(const short8*)(Bb + bBase + 512);
    vf[0] = *(const short8*)(Bb + 2048 + bBase);
    vf[1] = *(const short8*)(Bb + 2048 + bBase + 512);
#pragma unroll
    for (int bb = 0; bb < 2; ++bb) {
#pragma unroll
      for (int m = 0; m < 4; ++m)
        af[m] = *(const short8*)(Ab + bb * 8192 + aBase + m * 512);
      __builtin_amdgcn_s_setprio(1);
#pragma unroll
      for (int m = 0; m < 4; ++m)
#pragma unroll
        for (int n = 0; n < 2; ++n) {
          accK[bb][m][n] = __builtin_amdgcn_mfma_f32_16x16x32_bf16(af[m], kf[n], accK[bb][m][n], 0, 0, 0);
          accV[bb][m][n] = __builtin_amdgcn_mfma_f32_16x16x32_bf16(af[m], vf[n], accV[bb][m][n], 0, 0, 0);
        }
      __builtin_amdgcn_s_setprio(0);
    }

    if ((p & 31) == 31) {  // pair complete: fold exp-weighted sums, reset acc
#pragma unroll
      for (int bb = 0; bb < 2; ++bb)
#pragma unroll
        for (int m = 0; m < 4; ++m)
#pragma unroll
          for (int n = 0; n < 2; ++n) {
#pragma unroll
            for (int r = 0; r < 4; ++r) {
              float nmr = __expf(accK[bb][m][n][r] + bkc[n] + wbc[n]);
              sumN[m][n][r] += nmr;
              sumWV[m][n][r] += nmr * (accV[bb][m][n][r] + bvc[n]);
            }
            accK[bb][m][n] = floatx4{0.f, 0.f, 0.f, 0.f};
            accV[bb][m][n] = floatx4{0.f, 0.f, 0.f, 0.f};
          }
    }

    if (p < 126) { asm volatile("s_waitcnt vmcnt(5)" ::: "memory"); }
    else         { asm volatile("s_waitcnt vmcnt(0)" ::: "memory"); }
    __builtin_amdgcn_s_barrier();
    cur = (cur == 2) ? 0 : cur + 1;
    stg = (stg == 2) ? 0 : stg + 1;
  }

  // C/D layout: col = lane&15, row = (lane>>4)*4 + r
#pragma unroll
  for (int m = 0; m < 4; ++m)
#pragma unroll
    for (int n = 0; n < 2; ++n)
#pragma unroll
      for (int r = 0; r < 4; ++r) {
        int t = t0 + wrow * 64 + m * 16 + (lane >> 4) * 4 + r;
        int h = h0 + wcol * 32 + n * 16 + (lane & 15);
        weighted[(size_t)t * H_ + h] = sumWV[m][n][r] / sumN[m][n][r];
      }
}

// K2: Q GEMM + sigmoid(Q)*weighted epilogue (R10, passed @~95us).
__global__ __launch_bounds__(512, 2) void q_kernel(
    const ushort* __restrict__ Am, const ushort* __restrict__ Bm,
    const float* __restrict__ bq, const float* __restrict__ weighted,
    float* __restrict__ out) {
  extern __shared__ ushort lds[];

  const int tid = threadIdx.x;
  const int lane = tid & 63;
  const int w = tid >> 6;     // 0..7
  const int wr = w >> 2;      // 0..1  (128-row granule)
  const int wc = w & 3;       // 0..3  (64-col granule)

  const int bid = blockIdx.x;               // 512 blocks
  const int lid = (bid & 7) * 64 + (bid >> 3);
  const int R0 = (lid >> 2) * 256;          // row-panel 0..127
  const int C0 = (lid & 3) * 256;           // col-panel 0..3

  const int r0 = tid >> 2;                       // 0..127
  const int lc = (tid & 3) ^ ((tid >> 3) & 3);
  const ushort* asrc = Am + (size_t)(R0 + r0) * D_ + lc * 8;
  const ushort* bsrc = Bm + (size_t)(C0 + r0) * D_ + lc * 8;

  auto stage = [&](int t) {  // 4 gloads/thread
    const int nb = t & 3;
    const int kt = t * 32;
    GLOAD16(asrc + kt, lds + nb * 8192 + tid * 8);
    GLOAD16(asrc + kt + (size_t)128 * D_, lds + nb * 8192 + (512 + tid) * 8);
    GLOAD16(bsrc + kt, lds + 32768 + nb * 8192 + tid * 8);
    GLOAD16(bsrc + kt + (size_t)128 * D_, lds + 32768 + nb * 8192 + (512 + tid) * 8);
  };

  const int baseA = wr * 128 + (lane & 15);
  const int baseB = wc * 64 + (lane & 15);
  const int aOff = baseA * 32 + ((lane >> 4) ^ ((baseA >> 1) & 3)) * 8;
  const int bOff = baseB * 32 + ((lane >> 4) ^ ((baseB >> 1) & 3)) * 8;

  floatx4 acc[8][4] = {};

  stage(0); stage(1);
  asm volatile("s_waitcnt vmcnt(4)" ::: "memory");  // tile 0 landed
  __builtin_amdgcn_s_barrier();

  const int NT = D_ / 32;  // 32
  for (int t = 0; t < NT; ++t) {
    if (t < NT - 2) stage(t + 2);
    const ushort* Ab = lds + (t & 3) * 8192;
    const ushort* Bb = lds + 32768 + (t & 3) * 8192;

    short8 b[4], a[8];
#pragma unroll
    for (int n = 0; n < 4; ++n) b[n] = *(const short8*)(Bb + bOff + n * 512);
#pragma unroll
    for (int m = 0; m < 8; ++m) a[m] = *(const short8*)(Ab + aOff + m * 512);
#pragma unroll
    for (int m = 0; m < 8; ++m)
#pragma unroll
      for (int n = 0; n < 4; ++n)
        acc[m][n] = __builtin_amdgcn_mfma_f32_16x16x32_bf16(a[m], b[n], acc[m][n], 0, 0, 0);

    if (t < NT - 2) { asm volatile("s_waitcnt vmcnt(4)" ::: "memory"); }
    else            { asm volatile("s_waitcnt vmcnt(0)" ::: "memory"); }
    __builtin_amdgcn_s_barrier();
  }

  // ---- epilogue: in-LDS transpose, 2 m-halves, coalesced stores ----
  const int lrb = wr * 64 + (lane >> 4) * 4;  // + mi*16 + r  (0..127)
  const int lcol = wc * 64 + (lane & 15);     // + n*16
#pragma unroll
  for (int mh = 0; mh < 2; ++mh) {
    if (mh) __builtin_amdgcn_s_barrier();
    float* lf = (float*)lds;  // 128 x 256 fp32 = 128 KiB
#pragma unroll
    for (int mi = 0; mi < 4; ++mi)
#pragma unroll
      for (int n = 0; n < 4; ++n)
#pragma unroll
        for (int r = 0; r < 4; ++r)
          lf[(lrb + mi * 16 + r) * 256 + lcol + n * 16] = acc[mh * 4 + mi][n][r];
    __builtin_amdgcn_s_barrier();
#pragma unroll
    for (int j = 0; j < 16; ++j) {
      int cidx = j * 512 + tid;    // 0..8191 float4 chunks
      int lr = cidx >> 6;
      int cc = cidx & 63;
      int grow = R0 + (lr >> 6) * 128 + mh * 64 + (lr & 63);
      float4 v = *(float4*)(lf + lr * 256 + cc * 4);
      float4 bq4 = *(const float4*)(bq + C0 + cc * 4);
      float4 wv = *(const float4*)(weighted + (size_t)(grow & (T_ - 1)) * H_ + C0 + cc * 4);
      float4 o;
      o.x = wv.x / (1.f + __expf(-(v.x + bq4.x)));
      o.y = wv.y / (1.f + __expf(-(v.y + bq4.y)));
      o.z = wv.z / (1.f + __expf(-(v.z + bq4.z)));
      o.w = wv.w / (1.f + __expf(-(v.w + bq4.w)));
      *(float4*)(out + (size_t)grow * H_ + C0 + cc * 4) = o;
    }
  }
}

extern "C" void kernel_launch(void* const* d_in, const int* in_sizes, int n_in,
                              void* d_out, int out_size, void* d_ws, size_t ws_size,
                              hipStream_t stream) {
  (void)in_sizes; (void)n_in; (void)out_size; (void)ws_size;
  const float* x = (const float*)d_in[0];
  const float* Wq = (const float*)d_in[1];
  const float* bq = (const float*)d_in[2];
  const float* Wk = (const float*)d_in[3];
  const float* bk = (const float*)d_in[4];
  const float* Wv = (const float*)d_in[5];
  const float* bv = (const float*)d_in[6];
  const float* wbias = (const float*)d_in[7];
  float* out = (float*)d_out;

  char* ws = (char*)d_ws;
  const size_t XN = (size_t)B_ * T_ * D_;   // 33,554,432
  const size_t WN = (size_t)H_ * D_;        // 1,048,576
  ushort* xb  = (ushort*)ws;                             // 64 MiB
  ushort* Wqb = (ushort*)(ws + XN * 2);                  // 2 MiB
  ushort* Wkb = Wqb + WN;                                // 2 MiB
  ushort* Wvb = Wkb + WN;                                // 2 MiB
  float* weighted = (float*)(ws + XN * 2 + 3 * WN * 2);  // 16 MiB

  (void)hipFuncSetAttribute((const void*)kv_kernel,
                            hipFuncAttributeMaxDynamicSharedMemorySize, 122880);
  (void)hipFuncSetAttribute((const void*)q_kernel,
                            hipFuncAttributeMaxDynamicSharedMemorySize, 131072);

  cvt_kernel<<<2048, 256, 0, stream>>>(x, xb, (int)XN);
  cvt3_kernel<<<dim3(512, 3), 256, 0, stream>>>(Wq, Wk, Wv, Wqb, (int)WN);

  kv_kernel<<<256, 512, 122880, stream>>>(xb, Wkb, Wvb, bk, bv, wbias, weighted);
  q_kernel<<<512, 512, 131072, stream>>>(xb, Wqb, bq, weighted, out);
}